// Round 1
// baseline (11302.677 us; speedup 1.0000x reference)
//
#include <hip/hip_runtime.h>

#define D 64

__global__ void degree_kernel(const int* __restrict__ col, int* __restrict__ deg, int E) {
    int e = blockIdx.x * blockDim.x + threadIdx.x;
    if (e < E) atomicAdd(&deg[col[e]], 1);
}

__global__ void dinv_kernel(const int* __restrict__ deg, float* __restrict__ dinv, int n) {
    int i = blockIdx.x * blockDim.x + threadIdx.x;
    if (i < n) {
        int d = deg[i];
        dinv[i] = (d > 0) ? (1.0f / sqrtf((float)d)) : 0.0f;
    }
}

// Single-workgroup exclusive scan over N elements (runs once per call; ~90 chunks of 1024).
__global__ __launch_bounds__(1024) void scan_kernel(const int* __restrict__ deg,
                                                    int* __restrict__ row_ptr, int n) {
    __shared__ int wsum[16];
    const int tid = threadIdx.x;
    const int lane = tid & 63;
    const int w = tid >> 6;
    int carry = 0;
    for (int base = 0; base < n; base += 1024) {
        int i = base + tid;
        int v = (i < n) ? deg[i] : 0;
        int x = v;
#pragma unroll
        for (int off = 1; off < 64; off <<= 1) {
            int y = __shfl_up(x, off);
            if (lane >= off) x += y;
        }
        if (lane == 63) wsum[w] = x;
        __syncthreads();
        if (w == 0 && lane < 16) {
            int s = wsum[lane];
#pragma unroll
            for (int off = 1; off < 16; off <<= 1) {
                int y = __shfl_up(s, off);
                if (lane >= off) s += y;
            }
            wsum[lane] = s;
        }
        __syncthreads();
        int pref = (w > 0) ? wsum[w - 1] : 0;
        if (i < n) row_ptr[i] = carry + pref + (x - v);
        carry += wsum[15];
        __syncthreads();
    }
    if (tid == 0) row_ptr[n] = carry;
}

__global__ void scatter_kernel(const int* __restrict__ row, const int* __restrict__ col,
                               const float* __restrict__ dinv, const int* __restrict__ row_ptr,
                               int* __restrict__ cursor, int* __restrict__ csr_src,
                               float* __restrict__ csr_w, int E) {
    int e = blockIdx.x * blockDim.x + threadIdx.x;
    if (e < E) {
        int s = row[e];
        int d = col[e];
        int pos = row_ptr[d] + atomicAdd(&cursor[d], 1);
        csr_src[pos] = s;
        csr_w[pos] = dinv[s] * dinv[d];
    }
}

__global__ void copy_kernel(const float4* __restrict__ src, float4* __restrict__ dst, int n4) {
    int i = blockIdx.x * blockDim.x + threadIdx.x;
    if (i < n4) dst[i] = src[i];
}

// One wave per destination node. 4 edge-groups of 16 lanes; each lane loads a float4
// of x[src]. CSR (src,w) reads are software-pipelined one iteration ahead.
__global__ __launch_bounds__(256) void spmm_kernel(
    const float4* __restrict__ x_in, float4* __restrict__ x_out, float4* __restrict__ acc,
    const int* __restrict__ row_ptr, const int* __restrict__ csr_src,
    const float* __restrict__ csr_w, int n) {
    int wv = (int)((blockIdx.x * blockDim.x + threadIdx.x) >> 6);
    int lane = threadIdx.x & 63;
    if (wv >= n) return;
    int g = lane >> 4;   // edge subgroup 0..3
    int t = lane & 15;   // float4 slot within the 64-dim row
    int beg = row_ptr[wv], end = row_ptr[wv + 1];
    float sx = 0.f, sy = 0.f, sz = 0.f, sw = 0.f;

    int ee = beg + g;
    int s = 0; float wt = 0.f;
    if (ee < end) { s = csr_src[ee]; wt = csr_w[ee]; }
    for (int e = beg; e < end; e += 4) {
        int sc = s; float wc = wt;
        int en = e + 4 + g;
        s = 0; wt = 0.f;
        if (en < end) { s = csr_src[en]; wt = csr_w[en]; }
        float4 v = x_in[sc * 16 + t];
        sx += wc * v.x; sy += wc * v.y; sz += wc * v.z; sw += wc * v.w;
    }
    // reduce the 4 edge-groups (lanes differing in bits 4,5)
    sx += __shfl_xor(sx, 16); sy += __shfl_xor(sy, 16);
    sz += __shfl_xor(sz, 16); sw += __shfl_xor(sw, 16);
    sx += __shfl_xor(sx, 32); sy += __shfl_xor(sy, 32);
    sz += __shfl_xor(sz, 32); sw += __shfl_xor(sw, 32);
    if (g == 0) {
        int o = wv * 16 + t;
        float4 r; r.x = sx; r.y = sy; r.z = sz; r.w = sw;
        x_out[o] = r;
        float4 a = acc[o];
        a.x += sx; a.y += sy; a.z += sz; a.w += sw;
        acc[o] = a;
    }
}

__global__ void scale_kernel(float4* __restrict__ out, float f, int n4) {
    int i = blockIdx.x * blockDim.x + threadIdx.x;
    if (i < n4) {
        float4 a = out[i];
        a.x *= f; a.y *= f; a.z *= f; a.w *= f;
        out[i] = a;
    }
}

extern "C" void kernel_launch(void* const* d_in, const int* in_sizes, int n_in,
                              void* d_out, int out_size, void* d_ws, size_t ws_size,
                              hipStream_t stream) {
    const float* emb = (const float*)d_in[0];
    const int* eidx = (const int*)d_in[1];
    const int N = in_sizes[0] / D;   // 90000
    const int E = in_sizes[1] / 2;   // 3000000
    const int L = 100;
    const int* row = eidx;       // edge_index[0]
    const int* col = eidx + E;   // edge_index[1]

    size_t off = 0;
    auto alloc = [&](size_t bytes) -> void* {
        void* p = (char*)d_ws + off;
        off += (bytes + 255) & ~(size_t)255;
        return p;
    };
    int*   deg     = (int*)alloc((size_t)N * 4);
    float* dinv    = (float*)alloc((size_t)N * 4);
    int*   row_ptr = (int*)alloc((size_t)(N + 1) * 4);
    int*   cursor  = (int*)alloc((size_t)N * 4);
    int*   csr_src = (int*)alloc((size_t)E * 4);
    float* csr_w   = (float*)alloc((size_t)E * 4);
    float* xA      = (float*)alloc((size_t)N * D * 4);
    float* xB      = (float*)alloc((size_t)N * D * 4);

    hipMemsetAsync(deg, 0, (size_t)N * 4, stream);
    hipMemsetAsync(cursor, 0, (size_t)N * 4, stream);

    degree_kernel<<<(E + 255) / 256, 256, 0, stream>>>(col, deg, E);
    dinv_kernel<<<(N + 255) / 256, 256, 0, stream>>>(deg, dinv, N);
    scan_kernel<<<1, 1024, 0, stream>>>(deg, row_ptr, N);
    scatter_kernel<<<(E + 255) / 256, 256, 0, stream>>>(row, col, dinv, row_ptr, cursor,
                                                        csr_src, csr_w, E);

    float* out = (float*)d_out;
    const int n4 = N * D / 4;
    copy_kernel<<<(n4 + 255) / 256, 256, 0, stream>>>((const float4*)emb, (float4*)out, n4);

    const float4* xin = (const float4*)emb;
    float4* xout = (float4*)xA;
    for (int l = 0; l < L; ++l) {
        spmm_kernel<<<(N + 3) / 4, 256, 0, stream>>>(xin, xout, (float4*)out,
                                                     row_ptr, csr_src, csr_w, N);
        xin = (const float4*)xout;
        xout = (xout == (float4*)xA) ? (float4*)xB : (float4*)xA;
    }

    scale_kernel<<<(n4 + 255) / 256, 256, 0, stream>>>((float4*)out, 1.0f / (float)(L + 1), n4);
}